// Round 1
// 184.754 us; speedup vs baseline: 1.0112x; 1.0112x over previous
//
#include <hip/hip_runtime.h>
#include <cfloat>

// ---------------------------------------------------------------------------
// VectorQuantizer: z (16,256,32,32) f32, codebook (8192,256) f32
// outputs (f32 concat): z_q [4194304], loss [1], idx-as-float [16384]
// Validated semantics (R2-R6): idx = argmin_k fl32(zsq - 2*dot32(z,e_k)),
// lowest-index tie-break; bf16-MFMA coarse top-4 x 8 slices -> 32 cands/row;
// prune to coarse margin of row max; survivors re-scored fp64->fp32.
// R7: async double-buffered LDS, 64 z-rows/wave, tagged-float epilogue.
// R8: (a) full XOR swizzle incl. row bit-3 (kills the uniform 2-way bank
//     conflict on ds_read_b128); (b) zt pre-scaled by 2^21 + bias-in-MFMA-C
//     (drops the per-score fmaf: 4 VALU/score); (c) epilogue software-
//     pipelined: cf0 half interleaved into cf1 MFMA loop, cf1 half deferred
//     across the barrier into the next chunk (fills VALU pipe under MFMA);
//     (d) chunk-invariant LDS read addresses precomputed, buffer/cf folded
//     into ds_read offset immediates via x2-unrolled chunk loop.
// ---------------------------------------------------------------------------

#define NROWS 16384
#define NCODE 8192
#define DIMC  256
#define HW    1024
#define ZQN   4194304

// scratch inside d_out's z_q region (dead before zq_kernel overwrites):
#define ZT_OFF   0         // bf16 z*2^21 [16384][256] as ushort = 2097152 floats
#define CBT_OFF  2097152   // bf16 codebook [8192][256]          = 1048576 floats
#define ZSQ_OFF  3145728   // 16384 floats
#define CAND_OFF 3162112   // 8 slices * 16384 rows * 4 packed uints
#define LOSS_OFF ZQN
#define IDX_OFF  (ZQN + 1)

#define NSLICE 8
#define PRUNE_T 4300u      // key units (8 float-ulps each, worst 1.49e-8 dot):
                           // covers d-bin 3.05e-5 + 2x6sigma bf16 + tag-quant
                           // (+ <1 unit from bias-in-C accumulation rounding)
#define ZSCALE 2097152.0f  // 2^21, exact in bf16/f32

typedef __attribute__((ext_vector_type(8))) short bf16x8;
typedef __attribute__((ext_vector_type(4))) float f32x4;
typedef __attribute__((ext_vector_type(4))) unsigned int uint4v;

__device__ __forceinline__ unsigned umax(unsigned a, unsigned b) { return a > b ? a : b; }
__device__ __forceinline__ unsigned umin(unsigned a, unsigned b) { return a < b ? a : b; }

__device__ __forceinline__ unsigned short f2bf(float f) {   // RNE
    unsigned u = __float_as_uint(f);
    return (unsigned short)((u + 0x7fffu + ((u >> 16) & 1u)) >> 16);
}

#define GLD_LDS16(gptr, lptr) \
  __builtin_amdgcn_global_load_lds((const __attribute__((address_space(1))) unsigned int*)(const void*)(gptr), \
                                   (__attribute__((address_space(3))) unsigned int*)(lptr), 16, 0, 0)

// --- 1: fused prep: zt transpose+cvt(*2^21) | cbt cvt | zsq | loss zero ----
__global__ void prep_kernel(const float* __restrict__ z, const float* __restrict__ cb,
                            float* __restrict__ out) {
    int bid = blockIdx.x;
    int tid = threadIdx.x;
    if (bid < 1024) {
        __shared__ unsigned short lds[64 * 65];
        unsigned short* zt = (unsigned short*)(out + ZT_OFF);
        int c0 = (bid & 3) * 64;
        int n0 = (bid >> 2) * 64;
        const float* zb = z + (size_t)(n0 >> 10) * (DIMC * HW) + (n0 & 1023);
        #pragma unroll
        for (int i = 0; i < 4; ++i) {
            int f = tid + i * 256;
            int cl = f >> 4, n4 = f & 15;
            float4 v = *(const float4*)(zb + (size_t)(c0 + cl) * HW + n4 * 4);
            lds[(n4 * 4 + 0) * 65 + cl] = f2bf(v.x * ZSCALE);
            lds[(n4 * 4 + 1) * 65 + cl] = f2bf(v.y * ZSCALE);
            lds[(n4 * 4 + 2) * 65 + cl] = f2bf(v.z * ZSCALE);
            lds[(n4 * 4 + 3) * 65 + cl] = f2bf(v.w * ZSCALE);
        }
        __syncthreads();
        #pragma unroll
        for (int i = 0; i < 2; ++i) {
            int f = tid + i * 256;
            int nl = f >> 3, oct = f & 7;
            const unsigned short* p = lds + nl * 65 + oct * 8;
            uint4v u;
            u.x = (unsigned)p[0] | ((unsigned)p[1] << 16);
            u.y = (unsigned)p[2] | ((unsigned)p[3] << 16);
            u.z = (unsigned)p[4] | ((unsigned)p[5] << 16);
            u.w = (unsigned)p[6] | ((unsigned)p[7] << 16);
            *(uint4v*)(zt + (size_t)(n0 + nl) * DIMC + c0 + oct * 8) = u;
        }
    } else if (bid < 2048) {
        unsigned short* cbt = (unsigned short*)(out + CBT_OFF);
        size_t t = (size_t)(bid - 1024) * 256 + tid;
        float4 a = *(const float4*)(cb + t * 8);
        float4 b = *(const float4*)(cb + t * 8 + 4);
        uint4v u;
        u.x = (unsigned)f2bf(a.x) | ((unsigned)f2bf(a.y) << 16);
        u.y = (unsigned)f2bf(a.z) | ((unsigned)f2bf(a.w) << 16);
        u.z = (unsigned)f2bf(b.x) | ((unsigned)f2bf(b.y) << 16);
        u.w = (unsigned)f2bf(b.z) | ((unsigned)f2bf(b.w) << 16);
        *(uint4v*)(cbt + t * 8) = u;
        if (bid == 1024 && tid == 0) out[LOSS_OFF] = 0.0f;
    } else {
        int n = (bid - 2048) * 256 + tid;
        const float* zp = z + (size_t)(n >> 10) * (DIMC * HW) + (n & 1023);
        double s = 0.0;
        for (int c = 0; c < DIMC; ++c) {
            double v = (double)zp[(size_t)c * HW];
            s += v * v;
        }
        out[ZSQ_OFF + n] = (float)s;
    }
}

// --- 2: bf16 MFMA argmin: pipelined epilogue, conflict-free swizzle --------
// grid (64 row-blocks, 8 slices), 256 threads. Block: 256 rows x 1024 codes.
__global__ __launch_bounds__(256, 2)
void argmin_kernel(float* __restrict__ out) {
    __shared__ __align__(16) unsigned short a_s[2 * 32 * 256];   // 32 KB dbuf
    const unsigned short* zt  = (const unsigned short*)(out + ZT_OFF);
    const unsigned short* cbt = (const unsigned short*)(out + CBT_OFF);
    unsigned* cand = (unsigned*)(out + CAND_OFF);

    int tid = threadIdx.x;
    int lane = tid & 63;
    int wv = tid >> 6;
    int col = lane & 15, qk = lane >> 4;
    int n0 = blockIdx.x * 256;
    int slice = blockIdx.y;

    // B: wave's 64 z-rows (pre-scaled by 2^21) resident in registers
    bf16x8 B[4][8];
    #pragma unroll
    for (int rf = 0; rf < 4; ++rf)
        #pragma unroll
        for (int t = 0; t < 8; ++t)
            B[rf][t] = *(const bf16x8*)(zt + (size_t)(n0 + wv * 64 + rf * 16 + col) * DIMC
                                           + t * 32 + qk * 8);

    // staging sources: lane covers (row pair, 16B slot); full XOR swizzle
    // (row bits 0-2 AND bit 3 -> slot bits, matching read-side swizzle)
    int rl2 = lane >> 5;
    int jsl = lane & 31;
    const unsigned short* srcb[4];
    #pragma unroll
    for (int c = 0; c < 4; ++c) {
        int rloc = (wv * 4 + c) * 2 + rl2;
        int src16 = jsl ^ (rloc & 7) ^ ((rloc & 8) >> 1);
        srcb[c] = cbt + ((size_t)slice * 1024 + rloc) * DIMC + src16 * 8;
    }

    unsigned U1[4] = {0, 0, 0, 0}, U2[4] = {0, 0, 0, 0};

    // chunk-invariant per-lane LDS read addresses (buffer/cf via imm offset)
    const unsigned sb = (unsigned)((col & 7) ^ ((col & 8) >> 1));
    const unsigned short* aoff[8];
    #pragma unroll
    for (int t = 0; t < 8; ++t)
        aoff[t] = a_s + col * 256 + (((unsigned)(qk + 4 * t)) ^ sb) * 8;

    f32x4 acc[4][2];
    const f32x4 BIASV = (f32x4){131072.0f, 131072.0f, 131072.0f, 131072.0f};

    auto stage = [&](int ch, int dsto) {
        const size_t off = (size_t)ch * 32 * DIMC;
        unsigned short* dst = a_s + dsto;
        #pragma unroll
        for (int c = 0; c < 4; ++c)
            GLD_LDS16(srcb[c] + off, dst + (wv * 4 + c) * 512);
    };

    // deferred epilogue: cf=1 scores of the PREVIOUS chunk (tag base tb)
    auto epi1 = [&](unsigned tb) {
        #pragma unroll
        for (int rf = 0; rf < 4; ++rf)
            #pragma unroll
            for (int r = 0; r < 4; ++r) {
                unsigned bits = __float_as_uint(acc[rf][1][r]);
                unsigned u = (bits & 0xFFFFFF00u) | (tb - (unsigned)(4 + r));
                unsigned lo = umin(u, U1[rf]);
                U1[rf] = umax(u, U1[rf]);
                U2[rf] = umax(lo, U2[rf]);
            }
    };

    // one chunk: cf0 MFMAs, then cf1 MFMAs with cf0 epilogue interleaved
    auto compute = [&](int bufs /*shorts, compile-time*/, unsigned tb) {
        #pragma unroll
        for (int rf = 0; rf < 4; ++rf) acc[rf][0] = BIASV;
        #pragma unroll
        for (int t = 0; t < 8; ++t) {
            bf16x8 af = *(const bf16x8*)(aoff[t] + bufs);
            acc[0][0] = __builtin_amdgcn_mfma_f32_16x16x32_bf16(af, B[0][t], acc[0][0], 0, 0, 0);
            acc[1][0] = __builtin_amdgcn_mfma_f32_16x16x32_bf16(af, B[1][t], acc[1][0], 0, 0, 0);
            acc[2][0] = __builtin_amdgcn_mfma_f32_16x16x32_bf16(af, B[2][t], acc[2][0], 0, 0, 0);
            acc[3][0] = __builtin_amdgcn_mfma_f32_16x16x32_bf16(af, B[3][t], acc[3][0], 0, 0, 0);
        }
        #pragma unroll
        for (int rf = 0; rf < 4; ++rf) acc[rf][1] = BIASV;
        #pragma unroll
        for (int t = 0; t < 8; ++t) {
            bf16x8 af = *(const bf16x8*)(aoff[t] + bufs + 4096);
            acc[0][1] = __builtin_amdgcn_mfma_f32_16x16x32_bf16(af, B[0][t], acc[0][1], 0, 0, 0);
            acc[1][1] = __builtin_amdgcn_mfma_f32_16x16x32_bf16(af, B[1][t], acc[1][1], 0, 0, 0);
            acc[2][1] = __builtin_amdgcn_mfma_f32_16x16x32_bf16(af, B[2][t], acc[2][1], 0, 0, 0);
            acc[3][1] = __builtin_amdgcn_mfma_f32_16x16x32_bf16(af, B[3][t], acc[3][1], 0, 0, 0);
            {   // interleave: 2 cf0 scores of THIS chunk per t-step
                const int q0 = 2 * t, q1 = 2 * t + 1;
                const int rfA = q0 >> 2, rA = q0 & 3;
                const int rfB = q1 >> 2, rB = q1 & 3;
                unsigned bitsA = __float_as_uint(acc[rfA][0][rA]);
                unsigned uA = (bitsA & 0xFFFFFF00u) | (tb - (unsigned)rA);
                unsigned loA = umin(uA, U1[rfA]);
                U1[rfA] = umax(uA, U1[rfA]);
                U2[rfA] = umax(loA, U2[rfA]);
                unsigned bitsB = __float_as_uint(acc[rfB][0][rB]);
                unsigned uB = (bitsB & 0xFFFFFF00u) | (tb - (unsigned)rB);
                unsigned loB = umin(uB, U1[rfB]);
                U1[rfB] = umax(uB, U1[rfB]);
                U2[rfB] = umax(loB, U2[rfB]);
            }
        }
    };

    // prologue: stage chunk 0 into buffer 0
    stage(0, 0);
    __syncthreads();                  // drains GLD(0)
    stage(1, 8192);                   // prefetch chunk 1
    compute(0, 255u);                 // chunk 0 (buf0), cf1 epilogue deferred

    for (int ch = 1; ch < 31; ch += 2) {
        unsigned tb1 = 255u - ((unsigned)ch << 3);
        __syncthreads();              // chunk ch data ready; buf (ch+1)&1 free
        stage(ch + 1, 0);             // ch odd -> ch+1 even -> buf0
        epi1(tb1 + 8u);               // cf1 scores of chunk ch-1
        compute(8192, tb1);           // chunk ch (buf1)
        __syncthreads();
        stage(ch + 2, 8192);          // ch+2 odd -> buf1 (stages up to 31)
        epi1(tb1);                    // cf1 scores of chunk ch
        compute(0, tb1 - 8u);         // chunk ch+1 (buf0)
    }
    // chunk 31 (buf1): staged by the last loop iteration
    {
        __syncthreads();
        epi1(255u - (30u << 3));      // cf1 scores of chunk 30
        compute(8192, 255u - (31u << 3));
        epi1(255u - (31u << 3));      // cf1 scores of chunk 31
    }

    // decode to (key22<<10 | 1023-local), cross-qk merge top-4, store packed
    #pragma unroll
    for (int rf = 0; rf < 4; ++rf) {
        unsigned t1 = 255u - (U1[rf] & 255u);
        unsigned c1 = (t1 >> 3) * 32 + ((t1 >> 2) & 1) * 16 + qk * 4 + (t1 & 3);
        unsigned x1 = ((((U1[rf] & 0xFFFFFF00u) - 0x47000000u) >> 3) << 10) | (1023u - c1);
        unsigned t2 = 255u - (U2[rf] & 255u);
        unsigned c2 = (t2 >> 3) * 32 + ((t2 >> 2) & 1) * 16 + qk * 4 + (t2 & 3);
        unsigned x2 = ((((U2[rf] & 0xFFFFFF00u) - 0x47000000u) >> 3) << 10) | (1023u - c2);
        unsigned p1 = __shfl_xor(x1, 16);
        unsigned p2 = __shfl_xor(x2, 16);
        unsigned s1 = umax(x1, p1), tm = umin(x1, p1);
        unsigned ym = umax(x2, p2), s4 = umin(x2, p2);
        unsigned s2 = umax(tm, ym), s3 = umin(tm, ym);
        unsigned r1 = umax(s1, __shfl_xor(s4, 32));
        unsigned r2 = umax(s2, __shfl_xor(s3, 32));
        unsigned r3 = umax(s3, __shfl_xor(s2, 32));
        unsigned r4 = umax(s4, __shfl_xor(s1, 32));
        if (qk == 0) {
            int row = wv * 64 + rf * 16 + col;
            uint4v cw; cw.x = r1; cw.y = r2; cw.z = r3; cw.w = r4;
            *(uint4v*)(cand + ((size_t)slice * NROWS + n0 + row) * 4) = cw;
        }
    }
}

// --- 3: prune (coarse-key margin) + fp64 re-score survivors -----------------
// 2048 blocks x 256 threads; block = 8 rows x 32 candidates.
__global__ __launch_bounds__(256, 4)
void fixup_kernel(const float* __restrict__ z, const float* __restrict__ cb,
                  float* __restrict__ out) {
    __shared__ double zd[DIMC * 8];
    __shared__ float zsq_s[8];
    __shared__ unsigned qmx[8];
    __shared__ float dsc[32 * 8];
    __shared__ unsigned cds[32 * 8];
    int tid = threadIdx.x;
    int n0 = blockIdx.x * 8;
    const float* zb = z + (size_t)(n0 >> 10) * (DIMC * HW) + (n0 & 1023);
    int rr = tid & 7;
    #pragma unroll
    for (int i = 0; i < 8; ++i) {
        int c = (tid >> 3) + i * 32;
        zd[c * 8 + rr] = (double)zb[(size_t)c * HW + rr];
    }
    if (tid < 8) { zsq_s[tid] = out[ZSQ_OFF + n0 + tid]; qmx[tid] = 0; }
    int j = tid >> 3, r = tid & 7;
    unsigned w = ((const unsigned*)(out + CAND_OFF))
                 [(((size_t)(j >> 2)) * NROWS + n0 + r) * 4 + (j & 3)];
    unsigned qv = w >> 10;
    unsigned code = (unsigned)((j >> 2) * 1024) + 1023u - (w & 1023u);
    __syncthreads();
    atomicMax(&qmx[r], qv);
    __syncthreads();
    bool live = (qv + PRUNE_T >= qmx[r]);
    float d = FLT_MAX;
    if (live) {
        const float* e = cb + (size_t)code * DIMC;
        double a0 = 0.0, a1 = 0.0, a2 = 0.0, a3 = 0.0;
        for (int c = 0; c < DIMC; c += 16) {
            float4 e0 = *(const float4*)(e + c);
            float4 e1 = *(const float4*)(e + c + 4);
            float4 e2 = *(const float4*)(e + c + 8);
            float4 e3 = *(const float4*)(e + c + 12);
            a0 += zd[(c + 0) * 8 + r] * (double)e0.x + zd[(c + 1) * 8 + r] * (double)e0.y
                + zd[(c + 2) * 8 + r] * (double)e0.z + zd[(c + 3) * 8 + r] * (double)e0.w;
            a1 += zd[(c + 4) * 8 + r] * (double)e1.x + zd[(c + 5) * 8 + r] * (double)e1.y
                + zd[(c + 6) * 8 + r] * (double)e1.z + zd[(c + 7) * 8 + r] * (double)e1.w;
            a2 += zd[(c + 8) * 8 + r] * (double)e2.x + zd[(c + 9) * 8 + r] * (double)e2.y
                + zd[(c + 10) * 8 + r] * (double)e2.z + zd[(c + 11) * 8 + r] * (double)e2.w;
            a3 += zd[(c + 12) * 8 + r] * (double)e3.x + zd[(c + 13) * 8 + r] * (double)e3.y
                + zd[(c + 14) * 8 + r] * (double)e3.z + zd[(c + 15) * 8 + r] * (double)e3.w;
        }
        d = fmaf(-2.0f, (float)((a0 + a1) + (a2 + a3)), zsq_s[r]);
    }
    dsc[j * 8 + r] = d;
    cds[j * 8 + r] = code;
    __syncthreads();
    if (tid < 8) {
        float bd = FLT_MAX; unsigned bi = 0xffffffffu;
        for (int jj = 0; jj < 32; ++jj) {
            float dv = dsc[jj * 8 + tid];
            unsigned k = cds[jj * 8 + tid];
            if (dv < bd || (dv == bd && k < bi)) { bd = dv; bi = k; }
        }
        out[IDX_OFF + n0 + tid] = (float)bi;
    }
}

// --- 4: z_q via LDS-staged codebook rows + fused loss (atomicAdd) -----------
__global__ void zq_kernel(const float* __restrict__ z, const float* __restrict__ cb,
                          float* __restrict__ out) {
    __shared__ float lds[64 * 256];
    int tid = threadIdx.x;
    int n0 = blockIdx.x * 64;
    {
        int r = tid >> 2, q = tid & 3;
        int code = (int)out[IDX_OFF + n0 + r];
        const float* e = cb + (size_t)code * DIMC + q * 64;
        #pragma unroll
        for (int i = 0; i < 16; ++i) {
            float4 v = *(const float4*)(e + i * 4);
            int c4 = q * 16 + i;
            *(float4*)(lds + r * 256 + ((c4 ^ (r & 7)) * 4)) = v;
        }
    }
    __syncthreads();
    int hwl = tid & 63, g = tid >> 6;
    int b = n0 >> 10, hw0 = n0 & 1023;
    const size_t obase = (size_t)b * (DIMC * HW) + hw0 + hwl;
    float lsum = 0.f;
    #pragma unroll
    for (int i = 0; i < 16; ++i) {
        int c4 = g * 16 + i;
        float4 v = *(const float4*)(lds + hwl * 256 + ((c4 ^ (hwl & 7)) * 4));
        int c0 = c4 * 4;
        float z0 = z[obase + (size_t)(c0 + 0) * HW];
        float z1 = z[obase + (size_t)(c0 + 1) * HW];
        float z2 = z[obase + (size_t)(c0 + 2) * HW];
        float z3 = z[obase + (size_t)(c0 + 3) * HW];
        out[obase + (size_t)(c0 + 0) * HW] = v.x;
        out[obase + (size_t)(c0 + 1) * HW] = v.y;
        out[obase + (size_t)(c0 + 2) * HW] = v.z;
        out[obase + (size_t)(c0 + 3) * HW] = v.w;
        float d0 = v.x - z0, d1 = v.y - z1, d2 = v.z - z2, d3 = v.w - z3;
        lsum = fmaf(d0, d0, lsum); lsum = fmaf(d1, d1, lsum);
        lsum = fmaf(d2, d2, lsum); lsum = fmaf(d3, d3, lsum);
    }
    #pragma unroll
    for (int off = 32; off; off >>= 1) lsum += __shfl_down(lsum, off);
    __shared__ float red[4];
    if ((tid & 63) == 0) red[tid >> 6] = lsum;
    __syncthreads();
    if (tid == 0)
        atomicAdd(out + LOSS_OFF,
                  (red[0] + red[1] + red[2] + red[3]) * (1.25f / 4194304.0f));
}

extern "C" void kernel_launch(void* const* d_in, const int* in_sizes, int n_in,
                              void* d_out, int out_size, void* d_ws, size_t ws_size,
                              hipStream_t stream) {
    const float* z  = (const float*)d_in[0];
    const float* cb = (const float*)d_in[1];
    float* out = (float*)d_out;

    prep_kernel<<<2112, 256, 0, stream>>>(z, cb, out);
    argmin_kernel<<<dim3(64, NSLICE), 256, 0, stream>>>(out);
    fixup_kernel<<<NROWS / 8, 256, 0, stream>>>(z, cb, out);
    zq_kernel<<<256, 256, 0, stream>>>(z, cb, out);
}

// Round 2
// 184.481 us; speedup vs baseline: 1.0127x; 1.0015x over previous
//
#include <hip/hip_runtime.h>
#include <cfloat>

// ---------------------------------------------------------------------------
// VectorQuantizer: z (16,256,32,32) f32, codebook (8192,256) f32
// outputs (f32 concat): z_q [4194304], loss [1], idx-as-float [16384]
// Validated semantics (R2-R6): idx = argmin_k fl32(zsq - 2*dot32(z,e_k)),
// lowest-index tie-break; bf16-MFMA coarse top-4 x 8 slices -> 32 cands/row;
// prune to coarse margin of row max; survivors re-scored fp64->fp32.
// R7: async double-buffered LDS, 64 z-rows/wave, tagged-float epilogue.
// R8: pre-scaled zt (2^21) + bias-in-MFMA-C; epilogue software-pipelined.
//     (Bank-conflict counter proved structural: 4 cyc/b128 read, swizzle-
//      independent — not a lever.)
// R9: kill the per-chunk vmcnt(0) barrier drain (the ~1.6Kcyc/chunk stall):
//     triple-buffered LDS (48KB) + raw s_barrier + counted s_waitcnt vmcnt(4)
//     so the next chunk's 4 GLDs stay in flight ACROSS the barrier (T3/T4).
//     Each staging load now has ~2 chunk-phases to land. Buffer bases are
//     compile-time ds_read offset immediates via a group-of-3 chunk loop.
// ---------------------------------------------------------------------------

#define NROWS 16384
#define NCODE 8192
#define DIMC  256
#define HW    1024
#define ZQN   4194304

// scratch inside d_out's z_q region (dead before zq_kernel overwrites):
#define ZT_OFF   0         // bf16 z*2^21 [16384][256] as ushort = 2097152 floats
#define CBT_OFF  2097152   // bf16 codebook [8192][256]          = 1048576 floats
#define ZSQ_OFF  3145728   // 16384 floats
#define CAND_OFF 3162112   // 8 slices * 16384 rows * 4 packed uints
#define LOSS_OFF ZQN
#define IDX_OFF  (ZQN + 1)

#define NSLICE 8
#define PRUNE_T 4300u      // key units (8 float-ulps each, worst 1.49e-8 dot):
                           // covers d-bin 3.05e-5 + 2x6sigma bf16 + tag-quant
#define ZSCALE 2097152.0f  // 2^21, exact in bf16/f32

typedef __attribute__((ext_vector_type(8))) short bf16x8;
typedef __attribute__((ext_vector_type(4))) float f32x4;
typedef __attribute__((ext_vector_type(4))) unsigned int uint4v;

__device__ __forceinline__ unsigned umax(unsigned a, unsigned b) { return a > b ? a : b; }
__device__ __forceinline__ unsigned umin(unsigned a, unsigned b) { return a < b ? a : b; }

__device__ __forceinline__ unsigned short f2bf(float f) {   // RNE
    unsigned u = __float_as_uint(f);
    return (unsigned short)((u + 0x7fffu + ((u >> 16) & 1u)) >> 16);
}

#define GLD_LDS16(gptr, lptr) \
  __builtin_amdgcn_global_load_lds((const __attribute__((address_space(1))) unsigned int*)(const void*)(gptr), \
                                   (__attribute__((address_space(3))) unsigned int*)(lptr), 16, 0, 0)

// --- 1: fused prep: zt transpose+cvt(*2^21) | cbt cvt | zsq | loss zero ----
__global__ void prep_kernel(const float* __restrict__ z, const float* __restrict__ cb,
                            float* __restrict__ out) {
    int bid = blockIdx.x;
    int tid = threadIdx.x;
    if (bid < 1024) {
        __shared__ unsigned short lds[64 * 65];
        unsigned short* zt = (unsigned short*)(out + ZT_OFF);
        int c0 = (bid & 3) * 64;
        int n0 = (bid >> 2) * 64;
        const float* zb = z + (size_t)(n0 >> 10) * (DIMC * HW) + (n0 & 1023);
        #pragma unroll
        for (int i = 0; i < 4; ++i) {
            int f = tid + i * 256;
            int cl = f >> 4, n4 = f & 15;
            float4 v = *(const float4*)(zb + (size_t)(c0 + cl) * HW + n4 * 4);
            lds[(n4 * 4 + 0) * 65 + cl] = f2bf(v.x * ZSCALE);
            lds[(n4 * 4 + 1) * 65 + cl] = f2bf(v.y * ZSCALE);
            lds[(n4 * 4 + 2) * 65 + cl] = f2bf(v.z * ZSCALE);
            lds[(n4 * 4 + 3) * 65 + cl] = f2bf(v.w * ZSCALE);
        }
        __syncthreads();
        #pragma unroll
        for (int i = 0; i < 2; ++i) {
            int f = tid + i * 256;
            int nl = f >> 3, oct = f & 7;
            const unsigned short* p = lds + nl * 65 + oct * 8;
            uint4v u;
            u.x = (unsigned)p[0] | ((unsigned)p[1] << 16);
            u.y = (unsigned)p[2] | ((unsigned)p[3] << 16);
            u.z = (unsigned)p[4] | ((unsigned)p[5] << 16);
            u.w = (unsigned)p[6] | ((unsigned)p[7] << 16);
            *(uint4v*)(zt + (size_t)(n0 + nl) * DIMC + c0 + oct * 8) = u;
        }
    } else if (bid < 2048) {
        unsigned short* cbt = (unsigned short*)(out + CBT_OFF);
        size_t t = (size_t)(bid - 1024) * 256 + tid;
        float4 a = *(const float4*)(cb + t * 8);
        float4 b = *(const float4*)(cb + t * 8 + 4);
        uint4v u;
        u.x = (unsigned)f2bf(a.x) | ((unsigned)f2bf(a.y) << 16);
        u.y = (unsigned)f2bf(a.z) | ((unsigned)f2bf(a.w) << 16);
        u.z = (unsigned)f2bf(b.x) | ((unsigned)f2bf(b.y) << 16);
        u.w = (unsigned)f2bf(b.z) | ((unsigned)f2bf(b.w) << 16);
        *(uint4v*)(cbt + t * 8) = u;
        if (bid == 1024 && tid == 0) out[LOSS_OFF] = 0.0f;
    } else {
        int n = (bid - 2048) * 256 + tid;
        const float* zp = z + (size_t)(n >> 10) * (DIMC * HW) + (n & 1023);
        double s = 0.0;
        for (int c = 0; c < DIMC; ++c) {
            double v = (double)zp[(size_t)c * HW];
            s += v * v;
        }
        out[ZSQ_OFF + n] = (float)s;
    }
}

// --- 2: bf16 MFMA argmin: counted-vmcnt triple-buffer pipeline -------------
// grid (64 row-blocks, 8 slices), 256 threads. Block: 256 rows x 1024 codes.
__global__ __launch_bounds__(256, 2)
void argmin_kernel(float* __restrict__ out) {
    __shared__ __align__(16) unsigned short a_s[3 * 8192];   // 48 KB, 3 bufs
    const unsigned short* zt  = (const unsigned short*)(out + ZT_OFF);
    const unsigned short* cbt = (const unsigned short*)(out + CBT_OFF);
    unsigned* cand = (unsigned*)(out + CAND_OFF);

    int tid = threadIdx.x;
    int lane = tid & 63;
    int wv = tid >> 6;
    int col = lane & 15, qk = lane >> 4;
    int n0 = blockIdx.x * 256;
    int slice = blockIdx.y;

    // B: wave's 64 z-rows (pre-scaled by 2^21) resident in registers
    bf16x8 B[4][8];
    #pragma unroll
    for (int rf = 0; rf < 4; ++rf)
        #pragma unroll
        for (int t = 0; t < 8; ++t)
            B[rf][t] = *(const bf16x8*)(zt + (size_t)(n0 + wv * 64 + rf * 16 + col) * DIMC
                                           + t * 32 + qk * 8);

    // staging sources: lane covers (row pair, 16B slot); XOR swizzle
    int rl2 = lane >> 5;
    int jsl = lane & 31;
    const unsigned short* srcb[4];
    #pragma unroll
    for (int c = 0; c < 4; ++c) {
        int rloc = (wv * 4 + c) * 2 + rl2;
        int src16 = jsl ^ (rloc & 7) ^ ((rloc & 8) >> 1);
        srcb[c] = cbt + ((size_t)slice * 1024 + rloc) * DIMC + src16 * 8;
    }

    unsigned U1[4] = {0, 0, 0, 0}, U2[4] = {0, 0, 0, 0};

    // chunk-invariant per-lane LDS read addresses (buf/cf via imm offset)
    const unsigned sb = (unsigned)((col & 7) ^ ((col & 8) >> 1));
    const unsigned short* aoff[8];
    #pragma unroll
    for (int t = 0; t < 8; ++t)
        aoff[t] = a_s + col * 256 + (((unsigned)(qk + 4 * t)) ^ sb) * 8;

    f32x4 acc[4][2];
    const f32x4 BIASV = (f32x4){131072.0f, 131072.0f, 131072.0f, 131072.0f};

    auto stage = [&](int ch, int dsto /*shorts*/) {
        const size_t off = (size_t)ch * 32 * DIMC;
        unsigned short* dst = a_s + dsto;
        #pragma unroll
        for (int c = 0; c < 4; ++c)
            GLD_LDS16(srcb[c] + off, dst + (wv * 4 + c) * 512);
    };

    // deferred epilogue: cf=1 scores of the PREVIOUS chunk (tag base tb)
    auto epi1 = [&](unsigned tb) {
        #pragma unroll
        for (int rf = 0; rf < 4; ++rf)
            #pragma unroll
            for (int r = 0; r < 4; ++r) {
                unsigned bits = __float_as_uint(acc[rf][1][r]);
                unsigned u = (bits & 0xFFFFFF00u) | (tb - (unsigned)(4 + r));
                unsigned lo = umin(u, U1[rf]);
                U1[rf] = umax(u, U1[rf]);
                U2[rf] = umax(lo, U2[rf]);
            }
    };

    // one chunk: cf0 MFMAs, then cf1 MFMAs with cf0 epilogue interleaved.
    // bufb = compile-time byte base of this chunk's LDS buffer.
    auto compute = [&](int bufb, unsigned tb) {
        #pragma unroll
        for (int rf = 0; rf < 4; ++rf) acc[rf][0] = BIASV;
        #pragma unroll
        for (int t = 0; t < 8; ++t) {
            bf16x8 af = *(const bf16x8*)((const char*)aoff[t] + bufb);
            acc[0][0] = __builtin_amdgcn_mfma_f32_16x16x32_bf16(af, B[0][t], acc[0][0], 0, 0, 0);
            acc[1][0] = __builtin_amdgcn_mfma_f32_16x16x32_bf16(af, B[1][t], acc[1][0], 0, 0, 0);
            acc[2][0] = __builtin_amdgcn_mfma_f32_16x16x32_bf16(af, B[2][t], acc[2][0], 0, 0, 0);
            acc[3][0] = __builtin_amdgcn_mfma_f32_16x16x32_bf16(af, B[3][t], acc[3][0], 0, 0, 0);
        }
        #pragma unroll
        for (int rf = 0; rf < 4; ++rf) acc[rf][1] = BIASV;
        #pragma unroll
        for (int t = 0; t < 8; ++t) {
            bf16x8 af = *(const bf16x8*)((const char*)aoff[t] + bufb + 8192);
            acc[0][1] = __builtin_amdgcn_mfma_f32_16x16x32_bf16(af, B[0][t], acc[0][1], 0, 0, 0);
            acc[1][1] = __builtin_amdgcn_mfma_f32_16x16x32_bf16(af, B[1][t], acc[1][1], 0, 0, 0);
            acc[2][1] = __builtin_amdgcn_mfma_f32_16x16x32_bf16(af, B[2][t], acc[2][1], 0, 0, 0);
            acc[3][1] = __builtin_amdgcn_mfma_f32_16x16x32_bf16(af, B[3][t], acc[3][1], 0, 0, 0);
            {   // interleave: 2 cf0 scores of THIS chunk per t-step
                const int q0 = 2 * t, q1 = 2 * t + 1;
                const int rfA = q0 >> 2, rA = q0 & 3;
                const int rfB = q1 >> 2, rB = q1 & 3;
                unsigned bitsA = __float_as_uint(acc[rfA][0][rA]);
                unsigned uA = (bitsA & 0xFFFFFF00u) | (tb - (unsigned)rA);
                unsigned loA = umin(uA, U1[rfA]);
                U1[rfA] = umax(uA, U1[rfA]);
                U2[rfA] = umax(loA, U2[rfA]);
                unsigned bitsB = __float_as_uint(acc[rfB][0][rB]);
                unsigned uB = (bitsB & 0xFFFFFF00u) | (tb - (unsigned)rB);
                unsigned loB = umin(uB, U1[rfB]);
                U1[rfB] = umax(uB, U1[rfB]);
                U2[rfB] = umax(loB, U2[rfB]);
            }
        }
    };

    // barrier WITHOUT a full vmcnt drain: each wave proves its own oldest 4
    // GLDs (current chunk) landed; the newest 4 (next chunk) stay in flight.
#define CHUNK_SYNC(N)                                          \
    asm volatile("s_waitcnt vmcnt(" #N ")" ::: "memory");      \
    __builtin_amdgcn_s_barrier();                              \
    __builtin_amdgcn_sched_barrier(0);

    // prologue: stage chunks 0,1
    stage(0, 0);
    stage(1, 8192);

    // chunk 0 (buf0): drains B-loads + GLD(0), leaves GLD(1) in flight
    CHUNK_SYNC(4)
    stage(2, 16384);
    compute(0, 255u);

    // chunks 1..30 in groups of 3 (bufs 1,2,0); keep as a real loop so the
    // hot body (~3 chunks) stays I-cache resident.
    #pragma unroll 1
    for (int k = 0; k < 10; ++k) {
        const int c1 = 3 * k + 1;
        const unsigned tb = 255u - ((unsigned)c1 << 3);
        // chunk 3k+1 (buf1)
        CHUNK_SYNC(4)
        stage(c1 + 2, 0);
        epi1(tb + 8u);
        compute(16384, tb);
        // chunk 3k+2 (buf2)
        CHUNK_SYNC(4)
        stage(c1 + 3, 8192);
        epi1(tb);
        compute(32768, tb - 8u);
        // chunk 3k+3 (buf0)
        CHUNK_SYNC(4)
        if (k < 9) stage(c1 + 4, 16384);
        epi1(tb - 8u);
        compute(0, tb - 16u);
    }
    // chunk 31 (buf1): only GLD(31)'s 4 outstanding -> full drain
    CHUNK_SYNC(0)
    epi1(255u - (30u << 3));
    compute(16384, 255u - (31u << 3));
    epi1(255u - (31u << 3));
#undef CHUNK_SYNC

    // decode to (key22<<10 | 1023-local), cross-qk merge top-4, store packed
    #pragma unroll
    for (int rf = 0; rf < 4; ++rf) {
        unsigned t1 = 255u - (U1[rf] & 255u);
        unsigned c1 = (t1 >> 3) * 32 + ((t1 >> 2) & 1) * 16 + qk * 4 + (t1 & 3);
        unsigned x1 = ((((U1[rf] & 0xFFFFFF00u) - 0x47000000u) >> 3) << 10) | (1023u - c1);
        unsigned t2 = 255u - (U2[rf] & 255u);
        unsigned c2 = (t2 >> 3) * 32 + ((t2 >> 2) & 1) * 16 + qk * 4 + (t2 & 3);
        unsigned x2 = ((((U2[rf] & 0xFFFFFF00u) - 0x47000000u) >> 3) << 10) | (1023u - c2);
        unsigned p1 = __shfl_xor(x1, 16);
        unsigned p2 = __shfl_xor(x2, 16);
        unsigned s1 = umax(x1, p1), tm = umin(x1, p1);
        unsigned ym = umax(x2, p2), s4 = umin(x2, p2);
        unsigned s2 = umax(tm, ym), s3 = umin(tm, ym);
        unsigned r1 = umax(s1, __shfl_xor(s4, 32));
        unsigned r2 = umax(s2, __shfl_xor(s3, 32));
        unsigned r3 = umax(s3, __shfl_xor(s2, 32));
        unsigned r4 = umax(s4, __shfl_xor(s1, 32));
        if (qk == 0) {
            int row = wv * 64 + rf * 16 + col;
            uint4v cw; cw.x = r1; cw.y = r2; cw.z = r3; cw.w = r4;
            *(uint4v*)(cand + ((size_t)slice * NROWS + n0 + row) * 4) = cw;
        }
    }
}

// --- 3: prune (coarse-key margin) + fp64 re-score survivors -----------------
// 2048 blocks x 256 threads; block = 8 rows x 32 candidates.
__global__ __launch_bounds__(256, 4)
void fixup_kernel(const float* __restrict__ z, const float* __restrict__ cb,
                  float* __restrict__ out) {
    __shared__ double zd[DIMC * 8];
    __shared__ float zsq_s[8];
    __shared__ unsigned qmx[8];
    __shared__ float dsc[32 * 8];
    __shared__ unsigned cds[32 * 8];
    int tid = threadIdx.x;
    int n0 = blockIdx.x * 8;
    const float* zb = z + (size_t)(n0 >> 10) * (DIMC * HW) + (n0 & 1023);
    int rr = tid & 7;
    #pragma unroll
    for (int i = 0; i < 8; ++i) {
        int c = (tid >> 3) + i * 32;
        zd[c * 8 + rr] = (double)zb[(size_t)c * HW + rr];
    }
    if (tid < 8) { zsq_s[tid] = out[ZSQ_OFF + n0 + tid]; qmx[tid] = 0; }
    int j = tid >> 3, r = tid & 7;
    unsigned w = ((const unsigned*)(out + CAND_OFF))
                 [(((size_t)(j >> 2)) * NROWS + n0 + r) * 4 + (j & 3)];
    unsigned qv = w >> 10;
    unsigned code = (unsigned)((j >> 2) * 1024) + 1023u - (w & 1023u);
    __syncthreads();
    atomicMax(&qmx[r], qv);
    __syncthreads();
    bool live = (qv + PRUNE_T >= qmx[r]);
    float d = FLT_MAX;
    if (live) {
        const float* e = cb + (size_t)code * DIMC;
        double a0 = 0.0, a1 = 0.0, a2 = 0.0, a3 = 0.0;
        for (int c = 0; c < DIMC; c += 16) {
            float4 e0 = *(const float4*)(e + c);
            float4 e1 = *(const float4*)(e + c + 4);
            float4 e2 = *(const float4*)(e + c + 8);
            float4 e3 = *(const float4*)(e + c + 12);
            a0 += zd[(c + 0) * 8 + r] * (double)e0.x + zd[(c + 1) * 8 + r] * (double)e0.y
                + zd[(c + 2) * 8 + r] * (double)e0.z + zd[(c + 3) * 8 + r] * (double)e0.w;
            a1 += zd[(c + 4) * 8 + r] * (double)e1.x + zd[(c + 5) * 8 + r] * (double)e1.y
                + zd[(c + 6) * 8 + r] * (double)e1.z + zd[(c + 7) * 8 + r] * (double)e1.w;
            a2 += zd[(c + 8) * 8 + r] * (double)e2.x + zd[(c + 9) * 8 + r] * (double)e2.y
                + zd[(c + 10) * 8 + r] * (double)e2.z + zd[(c + 11) * 8 + r] * (double)e2.w;
            a3 += zd[(c + 12) * 8 + r] * (double)e3.x + zd[(c + 13) * 8 + r] * (double)e3.y
                + zd[(c + 14) * 8 + r] * (double)e3.z + zd[(c + 15) * 8 + r] * (double)e3.w;
        }
        d = fmaf(-2.0f, (float)((a0 + a1) + (a2 + a3)), zsq_s[r]);
    }
    dsc[j * 8 + r] = d;
    cds[j * 8 + r] = code;
    __syncthreads();
    if (tid < 8) {
        float bd = FLT_MAX; unsigned bi = 0xffffffffu;
        for (int jj = 0; jj < 32; ++jj) {
            float dv = dsc[jj * 8 + tid];
            unsigned k = cds[jj * 8 + tid];
            if (dv < bd || (dv == bd && k < bi)) { bd = dv; bi = k; }
        }
        out[IDX_OFF + n0 + tid] = (float)bi;
    }
}

// --- 4: z_q via LDS-staged codebook rows + fused loss (atomicAdd) -----------
__global__ void zq_kernel(const float* __restrict__ z, const float* __restrict__ cb,
                          float* __restrict__ out) {
    __shared__ float lds[64 * 256];
    int tid = threadIdx.x;
    int n0 = blockIdx.x * 64;
    {
        int r = tid >> 2, q = tid & 3;
        int code = (int)out[IDX_OFF + n0 + r];
        const float* e = cb + (size_t)code * DIMC + q * 64;
        #pragma unroll
        for (int i = 0; i < 16; ++i) {
            float4 v = *(const float4*)(e + i * 4);
            int c4 = q * 16 + i;
            *(float4*)(lds + r * 256 + ((c4 ^ (r & 7)) * 4)) = v;
        }
    }
    __syncthreads();
    int hwl = tid & 63, g = tid >> 6;
    int b = n0 >> 10, hw0 = n0 & 1023;
    const size_t obase = (size_t)b * (DIMC * HW) + hw0 + hwl;
    float lsum = 0.f;
    #pragma unroll
    for (int i = 0; i < 16; ++i) {
        int c4 = g * 16 + i;
        float4 v = *(const float4*)(lds + hwl * 256 + ((c4 ^ (hwl & 7)) * 4));
        int c0 = c4 * 4;
        float z0 = z[obase + (size_t)(c0 + 0) * HW];
        float z1 = z[obase + (size_t)(c0 + 1) * HW];
        float z2 = z[obase + (size_t)(c0 + 2) * HW];
        float z3 = z[obase + (size_t)(c0 + 3) * HW];
        out[obase + (size_t)(c0 + 0) * HW] = v.x;
        out[obase + (size_t)(c0 + 1) * HW] = v.y;
        out[obase + (size_t)(c0 + 2) * HW] = v.z;
        out[obase + (size_t)(c0 + 3) * HW] = v.w;
        float d0 = v.x - z0, d1 = v.y - z1, d2 = v.z - z2, d3 = v.w - z3;
        lsum = fmaf(d0, d0, lsum); lsum = fmaf(d1, d1, lsum);
        lsum = fmaf(d2, d2, lsum); lsum = fmaf(d3, d3, lsum);
    }
    #pragma unroll
    for (int off = 32; off; off >>= 1) lsum += __shfl_down(lsum, off);
    __shared__ float red[4];
    if ((tid & 63) == 0) red[tid >> 6] = lsum;
    __syncthreads();
    if (tid == 0)
        atomicAdd(out + LOSS_OFF,
                  (red[0] + red[1] + red[2] + red[3]) * (1.25f / 4194304.0f));
}

extern "C" void kernel_launch(void* const* d_in, const int* in_sizes, int n_in,
                              void* d_out, int out_size, void* d_ws, size_t ws_size,
                              hipStream_t stream) {
    const float* z  = (const float*)d_in[0];
    const float* cb = (const float*)d_in[1];
    float* out = (float*)d_out;

    prep_kernel<<<2112, 256, 0, stream>>>(z, cb, out);
    argmin_kernel<<<dim3(64, NSLICE), 256, 0, stream>>>(out);
    fixup_kernel<<<NROWS / 8, 256, 0, stream>>>(z, cb, out);
    zq_kernel<<<256, 256, 0, stream>>>(z, cb, out);
}